// Round 13
// baseline (328.783 us; speedup 1.0000x reference)
//
#include <hip/hip_runtime.h>
#include <hip/hip_bf16.h>

#define NN 100000
#define NE 1600000
#define ET (NE + NN)
#define NB 391          // buckets of 256 dst nodes
#define CAP 5120        // slots/bucket (mean 4352, +12 sigma)
#define BST 16          // bcnt pad: 64B per counter
#define NTILE (NN/16)   // 6250 gemm tiles

typedef __hip_bfloat16 bf16;
typedef __attribute__((ext_vector_type(8))) short short8;
typedef __attribute__((ext_vector_type(4))) float f32x4;

__device__ __forceinline__ unsigned short bfbits(float v){
    bf16 b = __float2bfloat16(v);
    return *(unsigned short*)&b;
}
__device__ __forceinline__ float fast_tanh(float x){
    float e = __expf(2.f*x);
    return 1.f - __fdividef(2.f, e + 1.f);
}

// ---------------- CSR build: bin by dst>>8 ----------------
__global__ void __launch_bounds__(256) k_bin(const int* __restrict__ src,
        const int* __restrict__ dst, int* __restrict__ bcnt,
        int* __restrict__ binbuf){
    __shared__ int cnt[NB];
    __shared__ int cur[NB];
    int t = threadIdx.x;
    for(int i=t;i<NB;i+=256) cnt[i]=0;
    __syncthreads();
    int e0 = blockIdx.x*2048;
    #pragma unroll
    for(int k=0;k<8;k++){
        int e = e0 + k*256 + t;
        if(e < ET){ int d = (e < NE) ? dst[e] : (e - NE); atomicAdd(&cnt[d>>8], 1); }
    }
    __syncthreads();
    for(int i=t;i<NB;i+=256){ int c=cnt[i]; cur[i] = c ? atomicAdd(&bcnt[i*BST], c) : 0; }
    __syncthreads();
    #pragma unroll
    for(int k=0;k<8;k++){
        int e = e0 + k*256 + t;
        if(e < ET){
            int s, d;
            if(e < NE){ s = src[e]; d = dst[e]; } else { s = e - NE; d = s; }
            int b = d >> 8;
            int pos = atomicAdd(&cur[b], 1);
            if(pos < CAP) binbuf[b*CAP + pos] = (s << 8) | (d & 255);
        }
    }
}

// ---------------- CSR build: per-bucket dense build (base prefix fused) ----------------
__global__ void __launch_bounds__(256) k_build(const int* __restrict__ bcnt,
        const int* __restrict__ binbuf, int* __restrict__ edge_src,
        int* __restrict__ rowst, int* __restrict__ deg){
    __shared__ int lsrc[CAP];
    __shared__ int ldeg[256], lscan[256], lcur[256], red[256];
    int b = blockIdx.x, t = threadIdx.x;
    int cnt = min(bcnt[b*BST], CAP);
    int part = 0;
    for(int i=t;i<b;i+=256) part += min(bcnt[i*BST], CAP);
    red[t] = part; __syncthreads();
    for(int off=128; off>=1; off>>=1){ if(t<off) red[t]+=red[t+off]; __syncthreads(); }
    int base = red[0];
    __syncthreads();
    ldeg[t] = 0; __syncthreads();
    const int* bb = binbuf + b*CAP;
    for(int i=t;i<cnt;i+=256) atomicAdd(&ldeg[bb[i] & 255], 1);
    __syncthreads();
    int dv = ldeg[t]; lscan[t] = dv; __syncthreads();
    for(int off=1; off<256; off<<=1){
        int u = (t>=off) ? lscan[t-off] : 0;
        __syncthreads(); lscan[t] += u; __syncthreads();
    }
    int excl = lscan[t] - dv; lcur[t] = excl;
    int node = b*256 + t;
    if(node < NN){ rowst[node] = base + excl; deg[node] = dv; }
    __syncthreads();
    for(int i=t;i<cnt;i+=256){
        int ent = bb[i];
        int pos = atomicAdd(&lcur[ent & 255], 1);
        lsrc[pos] = ent >> 8;
    }
    __syncthreads();
    for(int i=t;i<cnt;i+=256) edge_src[base+i] = lsrc[i];
}

// ---------------- h = x@W via MFMA, s_src, s_dst ----------------
// One 16-node tile per wave-iteration. A-frag straight from global; W as
// 8 short8 B-frags. D layout: col=lane&15, row=(lane>>4)*4+reg.
// h stored FP32 (no cvt, no unpack needed by the gather).

template<int FPIN>
__global__ void __launch_bounds__(256) k_gemm(const void* __restrict__ xin,
        const float* __restrict__ W, const float* __restrict__ avs,
        const float* __restrict__ avd, float* __restrict__ hb,
        float* __restrict__ ssrc, float* __restrict__ sdst){
    int tid = threadIdx.x, lane = tid & 63;
    int col = lane & 15, q = lane >> 4;
    short8 Bf[2][4];
    #pragma unroll
    for(int kh=0;kh<2;kh++){
        #pragma unroll
        for(int nb=0;nb<4;nb++){
            short8 b;
            #pragma unroll
            for(int j=0;j<8;j++){
                float w = W[(kh*32 + q*8 + j)*64 + nb*16 + col];
                b[j] = (short)bfbits(w);
            }
            Bf[kh][nb] = b;
        }
    }
    float as[4], ad[4];
    #pragma unroll
    for(int nb=0;nb<4;nb++){ as[nb] = avs[nb*16+col]; ad[nb] = avd[nb*16+col]; }

    int gw = (blockIdx.x*256 + tid) >> 6;
    int nwaves = gridDim.x*4;
    for(int tile = gw; tile < NTILE; tile += nwaves){
        int n0 = tile*16;
        f32x4 acc[4];
        #pragma unroll
        for(int nb=0;nb<4;nb++) acc[nb] = (f32x4){0.f,0.f,0.f,0.f};
        #pragma unroll
        for(int kh=0;kh<2;kh++){
            short8 a;
            if(FPIN){
                const float4* xr = (const float4*)((const float*)xin
                                    + (size_t)(n0+col)*64 + kh*32 + q*8);
                float4 u = xr[0], v = xr[1];
                a[0]=(short)bfbits(u.x); a[1]=(short)bfbits(u.y);
                a[2]=(short)bfbits(u.z); a[3]=(short)bfbits(u.w);
                a[4]=(short)bfbits(v.x); a[5]=(short)bfbits(v.y);
                a[6]=(short)bfbits(v.z); a[7]=(short)bfbits(v.w);
            } else {
                a = *(const short8*)((const bf16*)xin
                                    + (size_t)(n0+col)*64 + kh*32 + q*8);
            }
            #pragma unroll
            for(int nb=0;nb<4;nb++)
                acc[nb] = __builtin_amdgcn_mfma_f32_16x16x32_bf16(a, Bf[kh][nb], acc[nb], 0,0,0);
        }
        #pragma unroll
        for(int nb=0;nb<4;nb++){
            #pragma unroll
            for(int r=0;r<4;r++)
                hb[(size_t)(n0 + q*4 + r)*64 + nb*16 + col] = acc[nb][r];
        }
        #pragma unroll
        for(int r=0;r<4;r++){
            float ps = acc[0][r]*as[0] + acc[1][r]*as[1] + acc[2][r]*as[2] + acc[3][r]*as[3];
            float pd = acc[0][r]*ad[0] + acc[1][r]*ad[1] + acc[2][r]*ad[2] + acc[3][r]*ad[3];
            #pragma unroll
            for(int m=8;m>=1;m>>=1){ ps += __shfl_xor(ps,m); pd += __shfl_xor(pd,m); }
            if(col == 0){ ssrc[n0 + q*4 + r] = ps; sdst[n0 + q*4 + r] = pd; }
        }
    }
}

// ---------------- attention + aggregation ----------------
// wave per dst node; fp32 gather: float4 = 4 channels, 16 lanes cover the
// 256B row, 4 row-groups, 8 edges/iter (2 loads in flight). No unpack — 1
// FMA per channel. LDS (alpha,src) table; no max-pass (clamped exp).

template<int LAYER>
__global__ void __launch_bounds__(256) k_agg(
        const int* __restrict__ rowst, const int* __restrict__ deg,
        const int* __restrict__ edge_src,
        const float* __restrict__ ssrc, const float* __restrict__ sdst,
        const float* __restrict__ hb,
        const float* __restrict__ bias, const float* __restrict__ Wl,
        const float* __restrict__ bl,
        bf16* __restrict__ out1b, float* __restrict__ outF){
    __shared__ int2 pairs[256];
    int tid = threadIdx.x;
    int wid  = (blockIdx.x*256 + tid) >> 6;
    int lane = tid & 63;
    if(wid >= NN) return;
    int2* lp = pairs + (tid & 192);      // wave-private 64-entry table
    int rs = rowst[wid];
    int d  = deg[wid];
    float sd = sdst[wid];
    int grp = lane >> 4;                 // row-group 0..3
    int ch  = lane & 15;                 // channel chunk: channels ch*4..ch*4+3
    float a0=0.f, a1=0.f, a2=0.f, a3=0.f;

    if(d <= 64){
        int s = 0; float pr = 0.f;
        if(lane < d){
            s = edge_src[rs + lane];
            float t = ssrc[s] + sd;
            t = fmaxf(t, 0.2f*t);            // leaky_relu
            pr = __expf(fminf(t, 80.f));     // no max-shift: logits O(10)
        }
        float sm = pr;
        #pragma unroll
        for(int m=32;m>=1;m>>=1) sm += __shfl_xor(sm,m);
        float alpha = pr * (1.0f/(sm + 1e-16f));
        lp[lane] = make_int2(__float_as_int(alpha), s);   // lanes>=d: alpha=0
        for(int i0=0; i0<d; i0+=8){
            int2 e0 = lp[i0 + grp];
            int2 e1 = lp[i0 + 4 + grp];
            float f0 = __int_as_float(e0.x);
            float f1 = __int_as_float(e1.x);
            float4 k0 = ((const float4*)(hb + ((size_t)e0.y<<6)))[ch];
            float4 k1 = ((const float4*)(hb + ((size_t)e1.y<<6)))[ch];
            a0 += f0*k0.x; a1 += f0*k0.y; a2 += f0*k0.z; a3 += f0*k0.w;
            a0 += f1*k1.x; a1 += f1*k1.y; a2 += f1*k1.z; a3 += f1*k1.w;
        }
    } else {
        // generic path (d>64): keep max-shift for safety
        float lmax = -1e30f;
        for(int j=lane; j<d; j+=64){
            int sj = edge_src[rs+j];
            float t = ssrc[sj] + sd;
            lmax = fmaxf(lmax, fmaxf(t, 0.2f*t));
        }
        #pragma unroll
        for(int m=32;m>=1;m>>=1) lmax = fmaxf(lmax, __shfl_xor(lmax,m));
        float lsum = 0.f;
        for(int j=lane; j<d; j+=64){
            int sj = edge_src[rs+j];
            float t = ssrc[sj] + sd;
            lsum += __expf(fmaxf(t, 0.2f*t) - lmax);
        }
        #pragma unroll
        for(int m=32;m>=1;m>>=1) lsum += __shfl_xor(lsum,m);
        float inv = 1.0f/(lsum + 1e-16f);
        for(int cb=0; cb<d; cb+=64){
            int s2 = 0; float al = 0.f;
            int j = cb + lane;
            if(j < d){
                s2 = edge_src[rs+j];
                float t = ssrc[s2] + sd;
                al = __expf(fmaxf(t, 0.2f*t) - lmax) * inv;
            }
            lp[lane] = make_int2(__float_as_int(al), s2);
            int dd = min(d - cb, 64);
            for(int i0=0; i0<dd; i0+=8){
                int2 e0 = lp[i0 + grp];
                int2 e1 = lp[i0 + 4 + grp];
                float f0 = __int_as_float(e0.x);
                float f1 = __int_as_float(e1.x);
                float4 k0 = ((const float4*)(hb + ((size_t)e0.y<<6)))[ch];
                float4 k1 = ((const float4*)(hb + ((size_t)e1.y<<6)))[ch];
                a0 += f0*k0.x; a1 += f0*k0.y; a2 += f0*k0.z; a3 += f0*k0.w;
                a0 += f1*k1.x; a1 += f1*k1.y; a2 += f1*k1.z; a3 += f1*k1.w;
            }
        }
    }

    // fold over the 4 row-groups (lane bits 4..5)
    a0 += __shfl_xor(a0,32); a1 += __shfl_xor(a1,32);
    a2 += __shfl_xor(a2,32); a3 += __shfl_xor(a3,32);
    a0 += __shfl_xor(a0,16); a1 += __shfl_xor(a1,16);
    a2 += __shfl_xor(a2,16); a3 += __shfl_xor(a3,16);

    float4 bv = ((const float4*)bias)[ch];
    if(LAYER == 1){
        if(lane < 16){
            float v0 = fast_tanh(a0 + bv.x);
            float v1 = fast_tanh(a1 + bv.y);
            float v2 = fast_tanh(a2 + bv.z);
            float v3 = fast_tanh(a3 + bv.w);
            uint2 o;
            o.x = (unsigned)bfbits(v0) | ((unsigned)bfbits(v1) << 16);
            o.y = (unsigned)bfbits(v2) | ((unsigned)bfbits(v3) << 16);
            ((uint2*)(out1b + ((size_t)wid<<6)))[ch] = o;
        }
    } else {
        float4 wv = ((const float4*)Wl)[ch];
        float r = (a0+bv.x)*wv.x + (a1+bv.y)*wv.y + (a2+bv.z)*wv.z + (a3+bv.w)*wv.w;
        r += __shfl_xor(r,8); r += __shfl_xor(r,4);
        r += __shfl_xor(r,2); r += __shfl_xor(r,1);
        if(lane == 0) outF[wid] = r + bl[0];
    }
}

// ---------------- launch ----------------
extern "C" void kernel_launch(void* const* d_in, const int* in_sizes, int n_in,
                              void* d_out, int out_size, void* d_ws, size_t ws_size,
                              hipStream_t stream) {
    const float* x   = (const float*)d_in[0];
    const int*   ei  = (const int*)d_in[1];
    const float* W1  = (const float*)d_in[2];
    const float* as1 = (const float*)d_in[3];
    const float* ad1 = (const float*)d_in[4];
    const float* b1  = (const float*)d_in[5];
    const float* W2  = (const float*)d_in[6];
    const float* as2 = (const float*)d_in[7];
    const float* ad2 = (const float*)d_in[8];
    const float* b2  = (const float*)d_in[9];
    const float* Wl  = (const float*)d_in[10];
    const float* bl  = (const float*)d_in[11];
    float* out = (float*)d_out;

    const int* srcp = ei;
    const int* dstp = ei + NE;

    // workspace ~47 MB (round 2 proved ~60 MB OK)
    char* w = (char*)d_ws;
    int*   edge_src = (int*)w;  w += (size_t)ET*4;      //  6.8 MB
    float* hb       = (float*)w; w += (size_t)NN*64*4;  // 25.6 MB (fp32)
    bf16*  t1b      = (bf16*)w; w += (size_t)NN*64*2;   // 12.8 MB
    int*   rowst    = (int*)w;  w += (size_t)NN*4;
    int*   deg      = (int*)w;  w += (size_t)NN*4;
    float* ssrc     = (float*)w; w += (size_t)NN*4;
    float* sdst     = (float*)w; w += (size_t)NN*4;
    int*   bcnt     = (int*)w;  w += (size_t)NB*BST*4;
    int*   binbuf   = (int*)hb;     // aliases hb (8 MB <= 25.6): dead before k_gemm<1>

    const int nbBin = (ET + 2047)/2048;     // 831
    const int nbG   = 782;                  // 3128 waves -> ~2 tiles each
    const int nbA   = (NN + 3)/4;           // 25000

    hipMemsetAsync(bcnt, 0, (size_t)NB*BST*4, stream);
    k_bin  <<<nbBin, 256, 0, stream>>>(srcp, dstp, bcnt, binbuf);
    k_build<<<NB,    256, 0, stream>>>(bcnt, binbuf, edge_src, rowst, deg);

    // layer 1
    k_gemm<1><<<nbG, 256, 0, stream>>>((const void*)x, W1, as1, ad1, hb, ssrc, sdst);
    k_agg<1><<<nbA, 256, 0, stream>>>(rowst, deg, edge_src, ssrc, sdst, hb,
                                      b1, (const float*)nullptr, (const float*)nullptr,
                                      t1b, (float*)nullptr);
    // layer 2 + final linear
    k_gemm<0><<<nbG, 256, 0, stream>>>((const void*)t1b, W2, as2, ad2, hb, ssrc, sdst);
    k_agg<2><<<nbA, 256, 0, stream>>>(rowst, deg, edge_src, ssrc, sdst, hb,
                                      b2, Wl, bl,
                                      (bf16*)nullptr, out);
}

// Round 14
// 269.183 us; speedup vs baseline: 1.2214x; 1.2214x over previous
//
#include <hip/hip_runtime.h>
#include <hip/hip_bf16.h>

#define NN 100000
#define NE 1600000
#define ET (NE + NN)
#define NB 391          // buckets of 256 dst nodes
#define CAP 5120        // slots/bucket (mean 4352, +12 sigma)
#define BST 16          // bcnt pad: 64B per counter
#define NTILE (NN/16)   // 6250 gemm tiles
#define NBIN 831        // edge chunks of 2048
#define NGEM 782        // gemm blocks (3128 waves, ~2 tiles each)

typedef __hip_bfloat16 bf16;
typedef __attribute__((ext_vector_type(8))) short short8;
typedef __attribute__((ext_vector_type(4))) float f32x4;

__device__ __forceinline__ unsigned short bfbits(float v){
    bf16 b = __float2bfloat16(v);
    return *(unsigned short*)&b;
}
__device__ __forceinline__ float lo16(unsigned u){ return __uint_as_float(u<<16); }
__device__ __forceinline__ float hi16(unsigned u){ return __uint_as_float(u&0xffff0000u); }
__device__ __forceinline__ float fast_tanh(float x){
    float e = __expf(2.f*x);
    return 1.f - __fdividef(2.f, e + 1.f);
}

// ---------------- device: bin edges by dst>>8 (chunk = blockIdx-based) ----------------
__device__ void bin_phase(const int* __restrict__ src, const int* __restrict__ dst,
        int* __restrict__ bcnt, int* __restrict__ binbuf, int* smem, int chunk){
    int* cnt = smem; int* cur = smem + NB;
    int t = threadIdx.x;
    for(int i=t;i<NB;i+=256) cnt[i]=0;
    __syncthreads();
    int e0 = chunk*2048;
    #pragma unroll
    for(int k=0;k<8;k++){
        int e = e0 + k*256 + t;
        if(e < ET){ int d = (e < NE) ? dst[e] : (e - NE); atomicAdd(&cnt[d>>8], 1); }
    }
    __syncthreads();
    for(int i=t;i<NB;i+=256){ int c=cnt[i]; cur[i] = c ? atomicAdd(&bcnt[i*BST], c) : 0; }
    __syncthreads();
    #pragma unroll
    for(int k=0;k<8;k++){
        int e = e0 + k*256 + t;
        if(e < ET){
            int s, d;
            if(e < NE){ s = src[e]; d = dst[e]; } else { s = e - NE; d = s; }
            int b = d >> 8;
            int pos = atomicAdd(&cur[b], 1);
            if(pos < CAP) binbuf[b*CAP + pos] = (s << 8) | (d & 255);
        }
    }
}

// ---------------- device: h = x@W via MFMA, s_src, s_dst ----------------
// 16-node tile per wave-iter; A-frag from global; W as 8 short8 B-frags.
// D layout: col=lane&15, row=(lane>>4)*4+reg. h stored bf16.
template<int FPIN>
__device__ void gemm_phase(const void* __restrict__ xin,
        const float* __restrict__ W, const float* __restrict__ avs,
        const float* __restrict__ avd, bf16* __restrict__ hb,
        float* __restrict__ ssrc, float* __restrict__ sdst, int gw, int nwaves){
    int lane = threadIdx.x & 63;
    int col = lane & 15, q = lane >> 4;
    short8 Bf[2][4];
    #pragma unroll
    for(int kh=0;kh<2;kh++){
        #pragma unroll
        for(int nb=0;nb<4;nb++){
            short8 b;
            #pragma unroll
            for(int j=0;j<8;j++){
                float w = W[(kh*32 + q*8 + j)*64 + nb*16 + col];
                b[j] = (short)bfbits(w);
            }
            Bf[kh][nb] = b;
        }
    }
    float as[4], ad[4];
    #pragma unroll
    for(int nb=0;nb<4;nb++){ as[nb] = avs[nb*16+col]; ad[nb] = avd[nb*16+col]; }

    for(int tile = gw; tile < NTILE; tile += nwaves){
        int n0 = tile*16;
        f32x4 acc[4];
        #pragma unroll
        for(int nb=0;nb<4;nb++) acc[nb] = (f32x4){0.f,0.f,0.f,0.f};
        #pragma unroll
        for(int kh=0;kh<2;kh++){
            short8 a;
            if(FPIN){
                const float4* xr = (const float4*)((const float*)xin
                                    + (size_t)(n0+col)*64 + kh*32 + q*8);
                float4 u = xr[0], v = xr[1];
                a[0]=(short)bfbits(u.x); a[1]=(short)bfbits(u.y);
                a[2]=(short)bfbits(u.z); a[3]=(short)bfbits(u.w);
                a[4]=(short)bfbits(v.x); a[5]=(short)bfbits(v.y);
                a[6]=(short)bfbits(v.z); a[7]=(short)bfbits(v.w);
            } else {
                a = *(const short8*)((const bf16*)xin
                                    + (size_t)(n0+col)*64 + kh*32 + q*8);
            }
            #pragma unroll
            for(int nb=0;nb<4;nb++)
                acc[nb] = __builtin_amdgcn_mfma_f32_16x16x32_bf16(a, Bf[kh][nb], acc[nb], 0,0,0);
        }
        #pragma unroll
        for(int nb=0;nb<4;nb++){
            #pragma unroll
            for(int r=0;r<4;r++)
                hb[(size_t)(n0 + q*4 + r)*64 + nb*16 + col] = __float2bfloat16(acc[nb][r]);
        }
        #pragma unroll
        for(int r=0;r<4;r++){
            float ps = acc[0][r]*as[0] + acc[1][r]*as[1] + acc[2][r]*as[2] + acc[3][r]*as[3];
            float pd = acc[0][r]*ad[0] + acc[1][r]*ad[1] + acc[2][r]*ad[2] + acc[3][r]*ad[3];
            #pragma unroll
            for(int m=8;m>=1;m>>=1){ ps += __shfl_xor(ps,m); pd += __shfl_xor(pd,m); }
            if(col == 0){ ssrc[n0 + q*4 + r] = ps; sdst[n0 + q*4 + r] = pd; }
        }
    }
}

// ---------------- fused: bin (blocks 0..830)  ||  gemm1 (blocks 831..1612) ----------------
// Independent work, no inter-block sync needed. binbuf does NOT alias hb here.
__global__ void __launch_bounds__(256) k_binGemm(const int* __restrict__ src,
        const int* __restrict__ dst, int* __restrict__ bcnt, int* __restrict__ binbuf,
        const float* __restrict__ x, const float* __restrict__ W1,
        const float* __restrict__ as1, const float* __restrict__ ad1,
        bf16* __restrict__ hb, float* __restrict__ ssrc, float* __restrict__ sdst){
    __shared__ int smem[NB*2];
    if(blockIdx.x < NBIN){
        bin_phase(src, dst, bcnt, binbuf, smem, blockIdx.x);
    } else {
        int gw = (blockIdx.x - NBIN)*4 + (threadIdx.x >> 6);
        gemm_phase<1>((const void*)x, W1, as1, ad1, hb, ssrc, sdst, gw, NGEM*4);
    }
}

// ---------------- CSR build: per-bucket dense build (base prefix fused) ----------------
__global__ void __launch_bounds__(256) k_build(const int* __restrict__ bcnt,
        const int* __restrict__ binbuf, int* __restrict__ edge_src,
        int* __restrict__ rowst, int* __restrict__ deg){
    __shared__ int lsrc[CAP];
    __shared__ int ldeg[256], lscan[256], lcur[256], red[256];
    int b = blockIdx.x, t = threadIdx.x;
    int cnt = min(bcnt[b*BST], CAP);
    int part = 0;
    for(int i=t;i<b;i+=256) part += min(bcnt[i*BST], CAP);
    red[t] = part; __syncthreads();
    for(int off=128; off>=1; off>>=1){ if(t<off) red[t]+=red[t+off]; __syncthreads(); }
    int base = red[0];
    __syncthreads();
    ldeg[t] = 0; __syncthreads();
    const int* bb = binbuf + b*CAP;
    for(int i=t;i<cnt;i+=256) atomicAdd(&ldeg[bb[i] & 255], 1);
    __syncthreads();
    int dv = ldeg[t]; lscan[t] = dv; __syncthreads();
    for(int off=1; off<256; off<<=1){
        int u = (t>=off) ? lscan[t-off] : 0;
        __syncthreads(); lscan[t] += u; __syncthreads();
    }
    int excl = lscan[t] - dv; lcur[t] = excl;
    int node = b*256 + t;
    if(node < NN){ rowst[node] = base + excl; deg[node] = dv; }
    __syncthreads();
    for(int i=t;i<cnt;i+=256){
        int ent = bb[i];
        int pos = atomicAdd(&lcur[ent & 255], 1);
        lsrc[pos] = ent >> 8;
    }
    __syncthreads();
    for(int i=t;i<cnt;i+=256) edge_src[base+i] = lsrc[i];
}

// ---------------- standalone gemm (layer 2) ----------------
__global__ void __launch_bounds__(256) k_gemm2(const bf16* __restrict__ t1b,
        const float* __restrict__ W2, const float* __restrict__ as2,
        const float* __restrict__ ad2, bf16* __restrict__ hb,
        float* __restrict__ ssrc, float* __restrict__ sdst){
    int gw = (blockIdx.x*256 + threadIdx.x) >> 6;
    gemm_phase<0>((const void*)t1b, W2, as2, ad2, hb, ssrc, sdst, gw, NGEM*4);
}

// ---------------- attention + aggregation (round-10 verbatim: best measured) ----------------
// wave per dst node; uint2/lane = 4 channels, 4 row-groups, 8 edges/iter.
template<int LAYER>
__global__ void __launch_bounds__(256) k_agg(
        const int* __restrict__ rowst, const int* __restrict__ deg,
        const int* __restrict__ edge_src,
        const float* __restrict__ ssrc, const float* __restrict__ sdst,
        const bf16* __restrict__ hb,
        const float* __restrict__ bias, const float* __restrict__ Wl,
        const float* __restrict__ bl,
        bf16* __restrict__ out1b, float* __restrict__ outF){
    __shared__ int2 pairs[256];
    int tid = threadIdx.x;
    int wid  = (blockIdx.x*256 + tid) >> 6;
    int lane = tid & 63;
    if(wid >= NN) return;
    int2* lp = pairs + (tid & 192);
    int rs = rowst[wid];
    int d  = deg[wid];
    float sd = sdst[wid];
    int grp = lane >> 4;
    int ch  = lane & 15;
    float a0=0.f, a1=0.f, a2=0.f, a3=0.f;

    if(d <= 64){
        int s = 0; float p = 0.f;
        if(lane < d){
            s = edge_src[rs + lane];
            float t = ssrc[s] + sd;
            t = fmaxf(t, 0.2f*t);
            p = __expf(fminf(t, 80.f));
        }
        float sm = p;
        #pragma unroll
        for(int m=32;m>=1;m>>=1) sm += __shfl_xor(sm,m);
        float alpha = p * (1.0f/(sm + 1e-16f));
        lp[lane] = make_int2(__float_as_int(alpha), s);
        for(int i0=0; i0<d; i0+=8){
            int2 e0 = lp[i0 + grp];
            int2 e1 = lp[i0 + 4 + grp];
            float f0 = __int_as_float(e0.x);
            float f1 = __int_as_float(e1.x);
            uint2 k0 = ((const uint2*)(hb + ((size_t)e0.y<<6)))[ch];
            uint2 k1 = ((const uint2*)(hb + ((size_t)e1.y<<6)))[ch];
            a0 += f0*lo16(k0.x); a1 += f0*hi16(k0.x);
            a2 += f0*lo16(k0.y); a3 += f0*hi16(k0.y);
            a0 += f1*lo16(k1.x); a1 += f1*hi16(k1.x);
            a2 += f1*lo16(k1.y); a3 += f1*hi16(k1.y);
        }
    } else {
        float lmax = -1e30f;
        for(int j=lane; j<d; j+=64){
            int sj = edge_src[rs+j];
            float t = ssrc[sj] + sd;
            lmax = fmaxf(lmax, fmaxf(t, 0.2f*t));
        }
        #pragma unroll
        for(int m=32;m>=1;m>>=1) lmax = fmaxf(lmax, __shfl_xor(lmax,m));
        float lsum = 0.f;
        for(int j=lane; j<d; j+=64){
            int sj = edge_src[rs+j];
            float t = ssrc[sj] + sd;
            lsum += __expf(fmaxf(t, 0.2f*t) - lmax);
        }
        #pragma unroll
        for(int m=32;m>=1;m>>=1) lsum += __shfl_xor(lsum,m);
        float inv = 1.0f/(lsum + 1e-16f);
        for(int cb=0; cb<d; cb+=64){
            int s2 = 0; float al = 0.f;
            int j = cb + lane;
            if(j < d){
                s2 = edge_src[rs+j];
                float t = ssrc[s2] + sd;
                al = __expf(fmaxf(t, 0.2f*t) - lmax) * inv;
            }
            lp[lane] = make_int2(__float_as_int(al), s2);
            int dd = min(d - cb, 64);
            for(int i0=0; i0<dd; i0+=8){
                int2 e0 = lp[i0 + grp];
                int2 e1 = lp[i0 + 4 + grp];
                float f0 = __int_as_float(e0.x);
                float f1 = __int_as_float(e1.x);
                uint2 k0 = ((const uint2*)(hb + ((size_t)e0.y<<6)))[ch];
                uint2 k1 = ((const uint2*)(hb + ((size_t)e1.y<<6)))[ch];
                a0 += f0*lo16(k0.x); a1 += f0*hi16(k0.x);
                a2 += f0*lo16(k0.y); a3 += f0*hi16(k0.y);
                a0 += f1*lo16(k1.x); a1 += f1*hi16(k1.x);
                a2 += f1*lo16(k1.y); a3 += f1*hi16(k1.y);
            }
        }
    }

    a0 += __shfl_xor(a0,32); a1 += __shfl_xor(a1,32);
    a2 += __shfl_xor(a2,32); a3 += __shfl_xor(a3,32);
    a0 += __shfl_xor(a0,16); a1 += __shfl_xor(a1,16);
    a2 += __shfl_xor(a2,16); a3 += __shfl_xor(a3,16);

    float4 bv = ((const float4*)bias)[ch];
    if(LAYER == 1){
        if(lane < 16){
            float v0 = fast_tanh(a0 + bv.x);
            float v1 = fast_tanh(a1 + bv.y);
            float v2 = fast_tanh(a2 + bv.z);
            float v3 = fast_tanh(a3 + bv.w);
            uint2 o;
            o.x = (unsigned)bfbits(v0) | ((unsigned)bfbits(v1) << 16);
            o.y = (unsigned)bfbits(v2) | ((unsigned)bfbits(v3) << 16);
            ((uint2*)(out1b + ((size_t)wid<<6)))[ch] = o;
        }
    } else {
        float4 wv = ((const float4*)Wl)[ch];
        float r = (a0+bv.x)*wv.x + (a1+bv.y)*wv.y + (a2+bv.z)*wv.z + (a3+bv.w)*wv.w;
        r += __shfl_xor(r,8); r += __shfl_xor(r,4);
        r += __shfl_xor(r,2); r += __shfl_xor(r,1);
        if(lane == 0) outF[wid] = r + bl[0];
    }
}

// ---------------- launch ----------------
extern "C" void kernel_launch(void* const* d_in, const int* in_sizes, int n_in,
                              void* d_out, int out_size, void* d_ws, size_t ws_size,
                              hipStream_t stream) {
    const float* x   = (const float*)d_in[0];
    const int*   ei  = (const int*)d_in[1];
    const float* W1  = (const float*)d_in[2];
    const float* as1 = (const float*)d_in[3];
    const float* ad1 = (const float*)d_in[4];
    const float* b1  = (const float*)d_in[5];
    const float* W2  = (const float*)d_in[6];
    const float* as2 = (const float*)d_in[7];
    const float* ad2 = (const float*)d_in[8];
    const float* b2  = (const float*)d_in[9];
    const float* Wl  = (const float*)d_in[10];
    const float* bl  = (const float*)d_in[11];
    float* out = (float*)d_out;

    const int* srcp = ei;
    const int* dstp = ei + NE;

    // workspace ~42.2 MB; binbuf is its OWN region (bin runs concurrently
    // with gemm1's hb writes in k_binGemm — must not alias).
    char* w = (char*)d_ws;
    int*   edge_src = (int*)w;  w += (size_t)ET*4;        //  6.8 MB
    bf16*  hb       = (bf16*)w; w += (size_t)NN*64*2;     // 12.8 MB
    bf16*  t1b      = (bf16*)w; w += (size_t)NN*64*2;     // 12.8 MB
    int*   binbuf   = (int*)w;  w += (size_t)NB*CAP*4;    //  8.0 MB
    int*   rowst    = (int*)w;  w += (size_t)NN*4;
    int*   deg      = (int*)w;  w += (size_t)NN*4;
    float* ssrc     = (float*)w; w += (size_t)NN*4;
    float* sdst     = (float*)w; w += (size_t)NN*4;
    int*   bcnt     = (int*)w;  w += (size_t)NB*BST*4;

    const int nbA = (NN + 3)/4;           // 25000

    hipMemsetAsync(bcnt, 0, (size_t)NB*BST*4, stream);
    // bin (831 blocks) || gemm layer-1 (782 blocks) — independent
    k_binGemm<<<NBIN + NGEM, 256, 0, stream>>>(srcp, dstp, bcnt, binbuf,
                                               x, W1, as1, ad1, hb, ssrc, sdst);
    k_build<<<NB, 256, 0, stream>>>(bcnt, binbuf, edge_src, rowst, deg);

    k_agg<1><<<nbA, 256, 0, stream>>>(rowst, deg, edge_src, ssrc, sdst, hb,
                                      b1, (const float*)nullptr, (const float*)nullptr,
                                      t1b, (float*)nullptr);
    k_gemm2<<<NGEM, 256, 0, stream>>>(t1b, W2, as2, ad2, hb, ssrc, sdst);
    k_agg<2><<<nbA, 256, 0, stream>>>(rowst, deg, edge_src, ssrc, sdst, hb,
                                      b2, Wl, bl,
                                      (bf16*)nullptr, out);
}